// Round 2
// baseline (502.042 us; speedup 1.0000x reference)
//
#include <hip/hip_runtime.h>

// ParallelExperts MoE: out[t] = sum_j gates[t,j] * inputs[t] @ weight[e_{t,j}]^T
// N=262144, k=2, E=8, d=128.
// Two kernels, no atomics:
//   1) moe_mfma: blocks of 128 sorted positions (expert-uniform except ~7 run
//      boundaries). Gather token rows -> LDS f16, MFMA 16x16x32_f16 vs
//      weight[e] (L2-hot), write g*y as f16 into slot-indexed ws (plain stores).
//   2) combine: out[t] = ws[2t] + ws[2t+1] (fully coalesced, streaming).

#define D       128
#define TILE_P  128
#define LSTR    136      // LDS row stride (f16): 272 B, 16B-aligned rows
#define NTOK    262144
#define NK      (NTOK * 2)

typedef _Float16 halfx8 __attribute__((ext_vector_type(8)));
typedef _Float16 halfx4 __attribute__((ext_vector_type(4)));
typedef _Float16 halfx2 __attribute__((ext_vector_type(2)));
typedef float    floatx4 __attribute__((ext_vector_type(4)));

__global__ __launch_bounds__(256, 4)
void moe_mfma_kernel(const float* __restrict__ inputs,
                     const float* __restrict__ weight,
                     const float* __restrict__ gates,
                     const int*   __restrict__ sei,
                     const int*   __restrict__ ssi,
                     _Float16*    __restrict__ ws)
{
    __shared__ _Float16 As[TILE_P * LSTR];   // gathered token rows, f16
    __shared__ int   toks[TILE_P];
    __shared__ int   slots[TILE_P];
    __shared__ float gts[TILE_P];
    __shared__ int   eids[TILE_P];

    const int tid = threadIdx.x;
    const int p0  = blockIdx.x * TILE_P;

    if (tid < TILE_P) {
        int s = ssi[p0 + tid];
        slots[tid] = s;
        toks[tid]  = s >> 1;          // k == 2
        gts[tid]   = gates[s];        // gates flat [N*2]
        eids[tid]  = sei[p0 + tid];
    }
    __syncthreads();

    // Gather 128 token rows, fp32 -> f16 into LDS (one contiguous 512B row per half-wave).
    #pragma unroll
    for (int it = 0; it < 16; ++it) {
        int id = it * 256 + tid;         // 0..4095 float4 slots
        int r  = id >> 5;                // row 0..127
        int c4 = id & 31;                // float4 column
        float4 v = ((const float4*)inputs)[(size_t)toks[r] * 32 + c4];
        halfx4 h = { (_Float16)v.x, (_Float16)v.y, (_Float16)v.z, (_Float16)v.w };
        *(halfx4*)&As[r * LSTR + c4 * 4] = h;
    }

    const int uniform = __syncthreads_and((tid >= TILE_P) || (eids[tid] == eids[0]));

    const int lane = tid & 63;
    const int w    = tid >> 6;       // wave id 0..3
    const int m    = lane & 15;
    const int q    = lane >> 4;      // quad
    const int c0   = w * 32;         // this wave's output-column base

    int s0 = 0;
    while (s0 < TILE_P) {
        int e, s1;
        if (uniform) { e = eids[0]; s1 = TILE_P; }
        else {
            e = eids[s0]; s1 = s0 + 1;
            while (s1 < TILE_P && eids[s1] == e) ++s1;
        }

        // B fragments: lane m holds output cols c0+2m (ct=0) and c0+2m+1 (ct=1)
        // -> adjacent cols per lane, enabling packed half2 epilogue stores.
        halfx8 bf[2][4];
        #pragma unroll
        for (int ct = 0; ct < 2; ++ct) {
            const int o = c0 + 2 * m + ct;               // weight row = output col
            const float* wrow = weight + (size_t)e * (D * D) + (size_t)o * D;
            #pragma unroll
            for (int ks = 0; ks < 4; ++ks) {
                const int col = ks * 32 + q * 8;
                float4 v0 = *(const float4*)(wrow + col);
                float4 v1 = *(const float4*)(wrow + col + 4);
                halfx8 h = { (_Float16)v0.x, (_Float16)v0.y, (_Float16)v0.z, (_Float16)v0.w,
                             (_Float16)v1.x, (_Float16)v1.y, (_Float16)v1.z, (_Float16)v1.w };
                bf[ct][ks] = h;
            }
        }

        floatx4 acc[8][2];
        #pragma unroll
        for (int rt = 0; rt < 8; ++rt) {
            acc[rt][0] = {0.f, 0.f, 0.f, 0.f};
            acc[rt][1] = {0.f, 0.f, 0.f, 0.f};
        }

        #pragma unroll
        for (int ks = 0; ks < 4; ++ks) {
            const int kk = ks * 32 + q * 8;
            #pragma unroll
            for (int rt = 0; rt < 8; ++rt) {
                halfx8 a = *(const halfx8*)&As[(rt * 16 + m) * LSTR + kk];
                acc[rt][0] = __builtin_amdgcn_mfma_f32_16x16x32_f16(a, bf[0][ks], acc[rt][0], 0, 0, 0);
                acc[rt][1] = __builtin_amdgcn_mfma_f32_16x16x32_f16(a, bf[1][ks], acc[rt][1], 0, 0, 0);
            }
        }

        // Epilogue: D row = rt*16 + q*4 + r; lane's cols c0+2m / c0+2m+1.
        // Apply gate, pack half2, plain store to ws[slot].
        #pragma unroll
        for (int rt = 0; rt < 8; ++rt) {
            #pragma unroll
            for (int r = 0; r < 4; ++r) {
                int row = rt * 16 + q * 4 + r;
                if (row >= s0 && row < s1) {
                    float g = gts[row];
                    halfx2 h = { (_Float16)(acc[rt][0][r] * g),
                                 (_Float16)(acc[rt][1][r] * g) };
                    *(halfx2*)(ws + (size_t)slots[row] * D + c0 + 2 * m) = h;
                }
            }
        }
        s0 = s1;
    }
}

// out[t] = ws[2t] + ws[2t+1], 16 threads per token, 8 cols each.
__global__ __launch_bounds__(256)
void combine_kernel(const _Float16* __restrict__ ws, float* __restrict__ out)
{
    int gid = blockIdx.x * 256 + threadIdx.x;
    int t = gid >> 4;
    int j = (gid & 15) * 8;
    halfx8 a = *(const halfx8*)(ws + (size_t)(2 * t) * D + j);
    halfx8 b = *(const halfx8*)(ws + (size_t)(2 * t + 1) * D + j);
    float* dst = out + (size_t)t * D + j;
    float4 lo = { (float)a[0] + (float)b[0], (float)a[1] + (float)b[1],
                  (float)a[2] + (float)b[2], (float)a[3] + (float)b[3] };
    float4 hi = { (float)a[4] + (float)b[4], (float)a[5] + (float)b[5],
                  (float)a[6] + (float)b[6], (float)a[7] + (float)b[7] };
    *(float4*)dst = lo;
    *(float4*)(dst + 4) = hi;
}

extern "C" void kernel_launch(void* const* d_in, const int* in_sizes, int n_in,
                              void* d_out, int out_size, void* d_ws, size_t ws_size,
                              hipStream_t stream)
{
    const float* inputs = (const float*)d_in[0];   // [N, 128] fp32
    const float* weight = (const float*)d_in[1];   // [8, 128, 128] fp32
    const float* gates  = (const float*)d_in[2];   // [N, 2] fp32
    const int*   sei    = (const int*)d_in[4];     // sorted_expert_idxs [N*2]
    const int*   ssi    = (const int*)d_in[5];     // sorted_scattered_idxs [N*2]
    float*    out = (float*)d_out;
    _Float16* ws  = (_Float16*)d_ws;               // [N*2, 128] f16 (67 MB... 134 MB)

    moe_mfma_kernel<<<dim3(NK / TILE_P), dim3(256), 0, stream>>>(
        inputs, weight, gates, sei, ssi, ws);

    combine_kernel<<<dim3(NTOK * 16 / 256), dim3(256), 0, stream>>>(ws, out);
}

// Round 3
// 341.845 us; speedup vs baseline: 1.4686x; 1.4686x over previous
//
#include <hip/hip_runtime.h>

// ParallelExperts MoE: out[t] = sum_j gates[t,j] * inputs[t] @ weight[e_{t,j}]^T
// N=262144, k=2, E=8, d=128.
// Kernel 1 (moe_mfma): 128 sorted positions per block. Gather token rows ->
//   LDS f16, MFMA 16x16x32_f16 vs weight[e] (L2-hot). Epilogue stages g*y in
//   LDS (reusing the A buffer), then writes each slot row as ONE contiguous
//   256 B burst (full-line scattered stores -> no RMW/write amplification).
// Kernel 2 (combine): out[t] = ws[2t] + ws[2t+1], fully coalesced.

#define D       128
#define TILE_P  128
#define LSTR    136      // LDS row stride (f16): 272 B, 16B-aligned rows
#define NTOK    262144
#define NK      (NTOK * 2)

typedef _Float16 halfx8 __attribute__((ext_vector_type(8)));
typedef _Float16 halfx4 __attribute__((ext_vector_type(4)));
typedef _Float16 halfx2 __attribute__((ext_vector_type(2)));
typedef float    floatx4 __attribute__((ext_vector_type(4)));

__device__ __forceinline__ void load_bfrag(const float* __restrict__ weight,
                                           int e, int c0, int m, int q,
                                           halfx8 bf[2][4])
{
    // lane m holds output cols c0+2m (ct=0) and c0+2m+1 (ct=1); k = ks*32+q*8+j
    #pragma unroll
    for (int ct = 0; ct < 2; ++ct) {
        const int o = c0 + 2 * m + ct;                 // weight row = output col
        const float* wrow = weight + (size_t)e * (D * D) + (size_t)o * D;
        #pragma unroll
        for (int ks = 0; ks < 4; ++ks) {
            const int col = ks * 32 + q * 8;
            float4 v0 = *(const float4*)(wrow + col);
            float4 v1 = *(const float4*)(wrow + col + 4);
            halfx8 h = { (_Float16)v0.x, (_Float16)v0.y, (_Float16)v0.z, (_Float16)v0.w,
                         (_Float16)v1.x, (_Float16)v1.y, (_Float16)v1.z, (_Float16)v1.w };
            bf[ct][ks] = h;
        }
    }
}

__global__ __launch_bounds__(256, 4)
void moe_mfma_kernel(const float* __restrict__ inputs,
                     const float* __restrict__ weight,
                     const float* __restrict__ gates,
                     const int*   __restrict__ sei,
                     const int*   __restrict__ ssi,
                     _Float16*    __restrict__ ws)
{
    __shared__ _Float16 As[TILE_P * LSTR];   // A-tile; reused as Y (same stride) in epilogue
    __shared__ int   toks[TILE_P];
    __shared__ int   slots[TILE_P];
    __shared__ float gts[TILE_P];
    __shared__ int   eids[TILE_P];

    const int tid = threadIdx.x;
    const int p0  = blockIdx.x * TILE_P;

    if (tid < TILE_P) {
        int s = ssi[p0 + tid];
        slots[tid] = s;
        toks[tid]  = s >> 1;          // k == 2
        gts[tid]   = gates[s];        // gates flat [N*2]
        eids[tid]  = sei[p0 + tid];
    }
    __syncthreads();

    // Gather 128 token rows, fp32 -> f16 into LDS (contiguous 512 B per row).
    #pragma unroll
    for (int it = 0; it < 16; ++it) {
        int id = it * 256 + tid;         // 0..4095 float4 slots
        int r  = id >> 5;                // row 0..127
        int c4 = id & 31;                // float4 column
        float4 v = ((const float4*)inputs)[(size_t)toks[r] * 32 + c4];
        halfx4 h = { (_Float16)v.x, (_Float16)v.y, (_Float16)v.z, (_Float16)v.w };
        *(halfx4*)&As[r * LSTR + c4 * 4] = h;
    }

    const int uniform = __syncthreads_and((tid >= TILE_P) || (eids[tid] == eids[0]));

    const int lane = tid & 63;
    const int w    = tid >> 6;       // wave 0..3
    const int m    = lane & 15;
    const int q    = lane >> 4;
    const int c0   = w * 32;         // wave's output-column base

    floatx4 acc[8][2];
    #pragma unroll
    for (int rt = 0; rt < 8; ++rt) {
        acc[rt][0] = {0.f, 0.f, 0.f, 0.f};
        acc[rt][1] = {0.f, 0.f, 0.f, 0.f};
    }

    if (uniform) {
        // Common case: whole block one expert.
        halfx8 bf[2][4];
        load_bfrag(weight, eids[0], c0, m, q, bf);
        #pragma unroll
        for (int ks = 0; ks < 4; ++ks) {
            const int kk = ks * 32 + q * 8;
            #pragma unroll
            for (int rt = 0; rt < 8; ++rt) {
                halfx8 a = *(const halfx8*)&As[(rt * 16 + m) * LSTR + kk];
                acc[rt][0] = __builtin_amdgcn_mfma_f32_16x16x32_f16(a, bf[0][ks], acc[rt][0], 0, 0, 0);
                acc[rt][1] = __builtin_amdgcn_mfma_f32_16x16x32_f16(a, bf[1][ks], acc[rt][1], 0, 0, 0);
            }
        }
    } else {
        // Boundary block (~7 of 4096): per run, mask A rows outside the run
        // and accumulate — each D row receives only its own expert's product.
        int s0 = 0;
        while (s0 < TILE_P) {
            int e = eids[s0], s1 = s0 + 1;
            while (s1 < TILE_P && eids[s1] == e) ++s1;
            halfx8 bf[2][4];
            load_bfrag(weight, e, c0, m, q, bf);
            #pragma unroll
            for (int ks = 0; ks < 4; ++ks) {
                const int kk = ks * 32 + q * 8;
                #pragma unroll
                for (int rt = 0; rt < 8; ++rt) {
                    const int row = rt * 16 + m;
                    halfx8 a = {0,0,0,0,0,0,0,0};
                    if (row >= s0 && row < s1)
                        a = *(const halfx8*)&As[row * LSTR + kk];
                    acc[rt][0] = __builtin_amdgcn_mfma_f32_16x16x32_f16(a, bf[0][ks], acc[rt][0], 0, 0, 0);
                    acc[rt][1] = __builtin_amdgcn_mfma_f32_16x16x32_f16(a, bf[1][ks], acc[rt][1], 0, 0, 0);
                }
            }
            s0 = s1;
        }
    }

    __syncthreads();                 // all waves done reading As — safe to reuse as Y
    _Float16* Y = As;                // stride LSTR, 16B-aligned rows

    // Stage g*y into LDS: D row = rt*16 + q*4 + r; lane cols c0+2m, c0+2m+1.
    #pragma unroll
    for (int rt = 0; rt < 8; ++rt) {
        #pragma unroll
        for (int r = 0; r < 4; ++r) {
            int row = rt * 16 + q * 4 + r;
            float g = gts[row];
            halfx2 h = { (_Float16)(acc[rt][0][r] * g),
                         (_Float16)(acc[rt][1][r] * g) };
            *(halfx2*)&Y[row * LSTR + c0 + 2 * m] = h;
        }
    }
    __syncthreads();

    // Scattered full-row stores: 16 threads per row x 16 B = one 256 B burst
    // per slot row -> two fully-dirty 128 B lines, written exactly once.
    #pragma unroll
    for (int it = 0; it < 8; ++it) {
        int seg = it * 256 + tid;        // 0..2047
        int row = seg >> 4;              // 0..127
        int c8  = (seg & 15) * 8;        // f16 col 0..120
        halfx8 v = *(const halfx8*)&Y[row * LSTR + c8];
        *(halfx8*)(ws + (size_t)slots[row] * D + c8) = v;
    }
}

// out[t] = ws[2t] + ws[2t+1], fully coalesced.
__global__ __launch_bounds__(256)
void combine_kernel(const _Float16* __restrict__ ws, float* __restrict__ out)
{
    int gid = blockIdx.x * 256 + threadIdx.x;
    int t = gid >> 4;
    int j = (gid & 15) * 8;
    halfx8 a = *(const halfx8*)(ws + (size_t)(2 * t) * D + j);
    halfx8 b = *(const halfx8*)(ws + (size_t)(2 * t + 1) * D + j);
    float* dst = out + (size_t)t * D + j;
    float4 lo = { (float)a[0] + (float)b[0], (float)a[1] + (float)b[1],
                  (float)a[2] + (float)b[2], (float)a[3] + (float)b[3] };
    float4 hi = { (float)a[4] + (float)b[4], (float)a[5] + (float)b[5],
                  (float)a[6] + (float)b[6], (float)a[7] + (float)b[7] };
    *(float4*)dst = lo;
    *(float4*)(dst + 4) = hi;
}

extern "C" void kernel_launch(void* const* d_in, const int* in_sizes, int n_in,
                              void* d_out, int out_size, void* d_ws, size_t ws_size,
                              hipStream_t stream)
{
    const float* inputs = (const float*)d_in[0];   // [N, 128] fp32
    const float* weight = (const float*)d_in[1];   // [8, 128, 128] fp32
    const float* gates  = (const float*)d_in[2];   // [N, 2] fp32
    const int*   sei    = (const int*)d_in[4];     // sorted_expert_idxs [N*2]
    const int*   ssi    = (const int*)d_in[5];     // sorted_scattered_idxs [N*2]
    float*    out = (float*)d_out;
    _Float16* ws  = (_Float16*)d_ws;               // [N*2, 128] f16 = 134 MB

    moe_mfma_kernel<<<dim3(NK / TILE_P), dim3(256), 0, stream>>>(
        inputs, weight, gates, sei, ssi, ws);

    combine_kernel<<<dim3(NTOK * 16 / 256), dim3(256), 0, stream>>>(ws, out);
}